// Round 4
// baseline (1659.926 us; speedup 1.0000x reference)
//
#include <hip/hip_runtime.h>
#include <math.h>

// Problem constants
#define CC 256
#define HH_ 128
#define WW_ 128
#define HWP (HH_*WW_)           // 16384 pixels
#define TOK (64*HWP)            // 1,048,576 elems per (scale,batch) token matrix

// Workspace (us = bf16 elems):
//  qt/kt: [4 scale][4 b][tok][pix*64+ch]        16,777,216 each
//  vt   : [4 scale][4 b][d][tok] (all scales)   16,777,216
//  aot  : bf16 NHWC [b][y][x][c]                16,777,216
//  Sbf  : score buffer (reused; scale0 per-b)   16,777,216
//  wpack: conv weights [o][tap][c]                 589,824
//  wqkv : [3][o][c] bf16                           196,608
//  f32: stats[512], mstat[4096], linv[4096], S3[16384]

typedef __attribute__((ext_vector_type(8))) short bf16x8;
typedef __attribute__((ext_vector_type(4))) float f32x4;

__device__ __forceinline__ float bf2f(unsigned short u) {
    return __uint_as_float(((unsigned)u) << 16);
}
__device__ __forceinline__ unsigned short f2bf(float f) {
    unsigned u = __float_as_uint(f);
    u += 0x7FFF + ((u >> 16) & 1);
    return (unsigned short)(u >> 16);
}

union TileU {
    uint4 q[4];
    unsigned short u[32];
};

template<int ROWS>
__device__ __forceinline__ void tile_load(TileU& T, const unsigned short* src, int stride, int t) {
    if constexpr (ROWS == 128) {
        int r = t >> 1, kc = (t & 1) * 32;
        const uint4* sp = (const uint4*)(src + (size_t)r * stride + kc);
        T.q[0] = sp[0]; T.q[1] = sp[1]; T.q[2] = sp[2]; T.q[3] = sp[3];
    } else {
        int r = t >> 2, kc = (t & 3) * 16;
        const uint4* sp = (const uint4*)(src + (size_t)r * stride + kc);
        T.q[0] = sp[0]; T.q[1] = sp[1];
    }
}
template<int ROWS>
__device__ __forceinline__ void tile_store(unsigned short* lds, const TileU& T, int t) {
    if constexpr (ROWS == 128) {
        int r = t >> 1, kc = (t & 1) * 32;
        uint4* dp = (uint4*)&lds[r * 72 + kc];
        dp[0] = T.q[0]; dp[1] = T.q[1]; dp[2] = T.q[2]; dp[3] = T.q[3];
    } else {
        int r = t >> 2, kc = (t & 3) * 16;
        uint4* dp = (uint4*)&lds[r * 72 + kc];
        dp[0] = T.q[0]; dp[1] = T.q[1];
    }
}
template<int ROWS>
__device__ __forceinline__ void tile_exp(TileU& T, float m) {
    constexpr int n = (ROWS == 128) ? 32 : 16;
#pragma unroll
    for (int e = 0; e < n; e++) T.u[e] = f2bf(__expf(bf2f(T.u[e]) - m));
}

template<int IM, int JN>
__device__ __forceinline__ void mfma_iterT(const unsigned short* As, const unsigned short* Bs,
    int woffm, int woffn, int lr, int quad, f32x4 (&acc)[IM][JN])
{
#pragma unroll
    for (int s = 0; s < 2; s++) {
        bf16x8 af[IM], bfv[JN];
#pragma unroll
        for (int i = 0; i < IM; i++)
            af[i] = *(const bf16x8*)&As[(woffm + i * 16 + lr) * 72 + s * 32 + quad * 8];
#pragma unroll
        for (int j = 0; j < JN; j++)
            bfv[j] = *(const bf16x8*)&Bs[(woffn + j * 16 + lr) * 72 + s * 32 + quad * 8];
#pragma unroll
        for (int i = 0; i < IM; i++)
#pragma unroll
            for (int j = 0; j < JN; j++)
                acc[i][j] = __builtin_amdgcn_mfma_f32_16x16x32_bf16(af[i], bfv[j], acc[i][j], 0, 0, 0);
    }
}

// ---------------------------------------------------------------------------
__global__ __launch_bounds__(256) void zero_kernel(float* __restrict__ p)
{
    p[blockIdx.x * 256 + threadIdx.x] = 0.f;
}

// pack Wq/Wk/Wv fp32 -> bf16 [which][o][c]
__global__ __launch_bounds__(256) void pack_wqkv(
    const float* __restrict__ Wq, const float* __restrict__ Wk, const float* __restrict__ Wv,
    unsigned short* __restrict__ wqkv)
{
    int idx = blockIdx.x * 256 + threadIdx.x;          // 0..196607
    int which = idx >> 16, rem = idx & 65535;
    const float* W = (which == 0) ? Wq : (which == 1 ? Wk : Wv);
    wqkv[idx] = f2bf(W[rem]);
}

// pack conv weights: Wo [o][c][3][3] fp32 -> wpack [o][tap][c] bf16
__global__ __launch_bounds__(256) void wpack_kernel(
    const float* __restrict__ Wo, unsigned short* __restrict__ wpack)
{
    int o = blockIdx.x, c = threadIdx.x;
    const float* wr = Wo + ((size_t)o * CC + c) * 9;
#pragma unroll
    for (int tap = 0; tap < 9; tap++)
        wpack[((size_t)o * 9 + tap) * CC + c] = f2bf(wr[tap]);
}

// ---------------------------------------------------------------------------
// proj: C[ch][px] = W[ch][c] X[c][px]; epilogue via LDS transpose into
// token layouts. d-order inside token = (wy,wx,ch). Q/K: [tok][pix*64+ch];
// V: [d][tok]. grid: (128 px-row tiles, 2 ch-tiles, 12) z = which*4+b
__global__ __launch_bounds__(256) void proj_gemm(
    const float* __restrict__ x, const float* __restrict__ y,
    const unsigned short* __restrict__ wqkv,
    const float* __restrict__ bq, const float* __restrict__ bk, const float* __restrict__ bv,
    unsigned short* __restrict__ qt, unsigned short* __restrict__ kt,
    unsigned short* __restrict__ vt)
{
    __shared__ unsigned short SMEM[128 * 72 * 2];
    unsigned short* As = SMEM;
    unsigned short* Bs = SMEM + 128 * 72;
    unsigned short* CL = SMEM;   // reused: [px 128][ch 128] stride 136

    int z = blockIdx.z, b = z & 3, which = z >> 2;
    const float* src = ((which == 0) ? x : y) + (size_t)b * CC * HWP;
    const unsigned short* A = wqkv + which * 65536;
    const float* bias = (which == 0) ? bq : (which == 1 ? bk : bv);
    unsigned short* outp = (which == 0) ? qt : (which == 1 ? kt : vt);

    int n0 = blockIdx.x * 128;    // pixel base (full image row yy = n0>>7)
    int m0 = blockIdx.y * 128;    // channel base
    int my = blockIdx.y;

    int t = threadIdx.x, w = t >> 6, lane = t & 63;
    int quad = lane >> 4, lr = lane & 15;
    int woffm = (w >> 1) * 64, woffn = (w & 1) * 64;

    f32x4 acc[4][4];
#pragma unroll
    for (int i = 0; i < 4; i++)
#pragma unroll
        for (int j = 0; j < 4; j++) acc[i][j] = (f32x4){0.f, 0.f, 0.f, 0.f};

    int bc = t >> 2, bp0 = (t & 3) * 32;
    for (int c0 = 0; c0 < 256; c0 += 64) {
        TileU TA;
        tile_load<128>(TA, A + (size_t)m0 * 256 + c0, 256, t);
        float4 xb[8];
        const float* sp = src + (size_t)(c0 + bc) * HWP + n0 + bp0;
#pragma unroll
        for (int e = 0; e < 8; e++) xb[e] = *(const float4*)&sp[e * 4];
        __syncthreads();
        tile_store<128>(As, TA, t);
#pragma unroll
        for (int e = 0; e < 8; e++) {
            float4 v = xb[e];
            int p = bp0 + e * 4;
            Bs[(p + 0) * 72 + bc] = f2bf(v.x);
            Bs[(p + 1) * 72 + bc] = f2bf(v.y);
            Bs[(p + 2) * 72 + bc] = f2bf(v.z);
            Bs[(p + 3) * 72 + bc] = f2bf(v.w);
        }
        __syncthreads();
        mfma_iterT<4, 4>(As, Bs, woffm, woffn, lr, quad, acc);
        __syncthreads();
    }

    // stage transposed: CL[px][ch] = acc + bias
#pragma unroll
    for (int i = 0; i < 4; i++) {
        int chb = woffm + i * 16 + quad * 4;
        float b0 = bias[m0 + chb + 0], b1 = bias[m0 + chb + 1];
        float b2 = bias[m0 + chb + 2], b3 = bias[m0 + chb + 3];
#pragma unroll
        for (int j = 0; j < 4; j++) {
            int px = woffn + j * 16 + lr;
            ushort4 st;
            st.x = f2bf(acc[i][j][0] + b0);
            st.y = f2bf(acc[i][j][1] + b1);
            st.z = f2bf(acc[i][j][2] + b2);
            st.w = f2bf(acc[i][j][3] + b3);
            *(ushort4*)&CL[px * 136 + chb] = st;
        }
    }
    __syncthreads();

    int gy = n0 >> 7;   // image row
    if (which < 2) {
        // Q/K: per (pixel, scale-half): contiguous 64-ch segment
        int px = t >> 1, sh = t & 1;
        int s = my * 2 + sh, lg = s + 1, win = 1 << lg;
        int gp = n0 + px;
        int yy = gp >> 7, xx = gp & 127;
        int oy = yy >> lg, wy = yy & (win - 1);
        int ox = xx >> lg, wx = xx & (win - 1);
        size_t tok = (size_t)oy * (128 >> lg) + ox;
        unsigned short* qb = outp + ((size_t)s * 4 + b) * TOK;
        size_t dst = (tok * (win * win) + (wy * win + wx)) * 64;
        const uint4* spp = (const uint4*)&CL[px * 136 + sh * 64];
        uint4* dpp = (uint4*)&qb[dst];
#pragma unroll
        for (int e = 0; e < 8; e++) dpp[e] = spp[e];
    } else {
        // V: [d][tok] rows, contiguous token runs within this image row
#pragma unroll
        for (int sh = 0; sh < 2; sh++) {
            int s = my * 2 + sh, lg = s + 1, win = 1 << lg;
            int RL = 128 >> lg;                 // tokens per run in this row
            int ntok = (128 >> lg) * (128 >> lg);
            int oy = gy >> lg, wy = gy & (win - 1);
            unsigned short* vb = outp + ((size_t)s * 4 + b) * TOK;
            int chunk = RL < 32 ? RL : 32;
            int e0 = t * 32;
            for (int e = e0; e < e0 + 32; e += chunk) {
                int run = e >> (7 - lg);        // e / RL
                int pos = e & (RL - 1);
                int ch = run & 63, wx = run >> 6;
                union { unsigned short us_[32]; uint4 q_[4]; } buf;
                for (int kk = 0; kk < chunk; kk++) {
                    int px = (pos + kk) * win + wx;
                    buf.us_[kk] = CL[px * 136 + sh * 64 + ch];
                }
                size_t dst = ((size_t)(wy * win + wx) * 64 + ch) * ntok
                           + (size_t)oy * RL + pos;
                uint4* dpp = (uint4*)&vb[dst];
                for (int kk = 0; kk < chunk / 8; kk++) dpp[kk] = buf.q_[kk];
            }
        }
    }
}

// ---------------------------------------------------------------------------
// S[q][k] = sc * Q K^T. A=K-tile, B=Q-tile; transposed LDS epilogue gives
// row-major S with coalesced stores. grid: (NTOK/BN q, NTOK/BM k, nb)
template<int NTOK, int DD, int BM, int BN, int IM, int JN>
__global__ __launch_bounds__(256) void s_gemm(
    const unsigned short* __restrict__ Kb, const unsigned short* __restrict__ Qb,
    unsigned short* __restrict__ Sb, float sc)
{
    constexpr int SM1 = (BM + BN) * 72, SM2 = BN * 136;
    constexpr int SMSZ = SM1 > SM2 ? SM1 : SM2;
    __shared__ unsigned short SMEM[SMSZ];
    unsigned short* As = SMEM;
    unsigned short* Bs = SMEM + BM * 72;
    unsigned short* CL = SMEM;

    int bz = blockIdx.z;
    int n0q = blockIdx.x * BN, m0k = blockIdx.y * BM;
    const unsigned short* A = Kb + (size_t)bz * TOK + (size_t)m0k * DD;
    const unsigned short* B = Qb + (size_t)bz * TOK + (size_t)n0q * DD;
    unsigned short* S = Sb + (size_t)bz * NTOK * NTOK;

    int t = threadIdx.x, w = t >> 6, lane = t & 63;
    int quad = lane >> 4, lr = lane & 15;
    int woffm = (w >> 1) * (BM / 2), woffn = (w & 1) * (BN / 2);

    f32x4 acc[IM][JN];
#pragma unroll
    for (int i = 0; i < IM; i++)
#pragma unroll
        for (int j = 0; j < JN; j++) acc[i][j] = (f32x4){0.f, 0.f, 0.f, 0.f};

    for (int k0 = 0; k0 < DD; k0 += 64) {
        TileU TA, TB;
        tile_load<BM>(TA, A + k0, DD, t);
        tile_load<BN>(TB, B + k0, DD, t);
        __syncthreads();
        tile_store<BM>(As, TA, t);
        tile_store<BN>(Bs, TB, t);
        __syncthreads();
        mfma_iterT<IM, JN>(As, Bs, woffm, woffn, lr, quad, acc);
        __syncthreads();
    }

    // transposed stage: CL[q_local][k_local] = acc*sc
#pragma unroll
    for (int i = 0; i < IM; i++) {
        int kb = woffm + i * 16 + quad * 4;
#pragma unroll
        for (int j = 0; j < JN; j++) {
            int qrow = woffn + j * 16 + lr;
            ushort4 st;
            st.x = f2bf(acc[i][j][0] * sc);
            st.y = f2bf(acc[i][j][1] * sc);
            st.z = f2bf(acc[i][j][2] * sc);
            st.w = f2bf(acc[i][j][3] * sc);
            *(ushort4*)&CL[qrow * 136 + kb] = st;
        }
    }
    __syncthreads();

    if constexpr (BN == 128) {
        int row = t >> 1, half = t & 1;
        const uint4* spp = (const uint4*)&CL[row * 136 + half * 64];
        uint4* dpp = (uint4*)&S[(size_t)(n0q + row) * NTOK + m0k + half * 64];
#pragma unroll
        for (int e = 0; e < 8; e++) dpp[e] = spp[e];
    } else {
        int row = t >> 2, q4 = t & 3;
        const uint4* spp = (const uint4*)&CL[row * 136 + q4 * 16];
        uint4* dpp = (uint4*)&S[(size_t)(n0q + row) * NTOK + m0k + q4 * 16];
        dpp[0] = spp[0]; dpp[1] = spp[1];
    }
}

// ---------------------------------------------------------------------------
// per-row online (max, sum) of exp. one wave per row. grid: rows_total/4
__global__ __launch_bounds__(256) void row_stats(
    const unsigned short* __restrict__ S, float* __restrict__ mst,
    float* __restrict__ linv, int n)
{
    int wid = threadIdx.x >> 6, lane = threadIdx.x & 63;
    int row = blockIdx.x * 4 + wid;
    const unsigned short* rp = S + (size_t)row * n;
    float m = -1e30f, l = 0.f;
    for (int j = lane * 8; j < n; j += 512) {
        ushort4 u0 = *(const ushort4*)&rp[j];
        ushort4 u1 = *(const ushort4*)&rp[j + 4];
        float v[8] = {bf2f(u0.x), bf2f(u0.y), bf2f(u0.z), bf2f(u0.w),
                      bf2f(u1.x), bf2f(u1.y), bf2f(u1.z), bf2f(u1.w)};
        float mc = v[0];
#pragma unroll
        for (int e = 1; e < 8; e++) mc = fmaxf(mc, v[e]);
        float lc = 0.f;
#pragma unroll
        for (int e = 0; e < 8; e++) lc += __expf(v[e] - mc);
        if (mc > m) { l = l * __expf(m - mc) + lc; m = mc; }
        else        { l += lc * __expf(mc - m); }
    }
#pragma unroll
    for (int off = 1; off < 64; off <<= 1) {
        float mo = __shfl_xor(m, off);
        float lo = __shfl_xor(l, off);
        if (mo > m) { l = l * __expf(m - mo) + lo; m = mo; }
        else        { l += lo * __expf(mo - m); }
    }
    if (lane == 0) { mst[row] = m; linv[row] = 1.f / l; }
}

// ---------------------------------------------------------------------------
// O = softmax(S) V. A = S rows with exp(v-m) fused at load; epilogue *1/l,
// LDS-staged, coalesced NHWC stores. B = V[d][tok]. grid:(DD/128, NTOK/BM, nb)
template<int NTOK, int DD, int LG, int CH0, int BM, int IM, int JN>
__global__ __launch_bounds__(256) void o_gemm(
    const unsigned short* __restrict__ Pb, const unsigned short* __restrict__ Vb,
    const float* __restrict__ mstat, const float* __restrict__ linv,
    unsigned short* __restrict__ aot, int b0)
{
    constexpr int SM1 = (BM + 128) * 72, SM2 = BM * 136;
    constexpr int SMSZ = SM1 > SM2 ? SM1 : SM2;
    __shared__ unsigned short SMEM[SMSZ];
    unsigned short* As = SMEM;
    unsigned short* Bs = SMEM + BM * 72;
    unsigned short* CL = SMEM;

    int bz = blockIdx.z, b = b0 + bz;
    int n0 = blockIdx.x * 128, m0 = blockIdx.y * BM;
    const unsigned short* A = Pb + (size_t)bz * NTOK * NTOK + (size_t)m0 * NTOK;
    const unsigned short* V = Vb + (size_t)bz * TOK + (size_t)n0 * NTOK;
    const float* msp = mstat + bz * NTOK + m0;
    const float* lip = linv + bz * NTOK + m0;

    int t = threadIdx.x, w = t >> 6, lane = t & 63;
    int quad = lane >> 4, lr = lane & 15;
    int woffm = (w >> 1) * (BM / 2), woffn = (w & 1) * 64;

    float mrow = msp[(BM == 128) ? (t >> 1) : (t >> 2)];

    f32x4 acc[IM][JN];
#pragma unroll
    for (int i = 0; i < IM; i++)
#pragma unroll
        for (int j = 0; j < JN; j++) acc[i][j] = (f32x4){0.f, 0.f, 0.f, 0.f};

    for (int k0 = 0; k0 < NTOK; k0 += 64) {
        TileU TA, TB;
        tile_load<BM>(TA, A + k0, NTOK, t);
        tile_load<128>(TB, V + k0, NTOK, t);
        __syncthreads();
        tile_exp<BM>(TA, mrow);
        tile_store<BM>(As, TA, t);
        tile_store<128>(Bs, TB, t);
        __syncthreads();
        mfma_iterT<IM, JN>(As, Bs, woffm, woffn, lr, quad, acc);
        __syncthreads();
    }

    // stage CL[m][n] = acc * 1/l
#pragma unroll
    for (int i = 0; i < IM; i++) {
        int mb = woffm + i * 16 + quad * 4;
        float l0 = lip[mb + 0], l1 = lip[mb + 1], l2 = lip[mb + 2], l3 = lip[mb + 3];
#pragma unroll
        for (int j = 0; j < JN; j++) {
            int nc = woffn + j * 16 + lr;
            CL[(mb + 0) * 136 + nc] = f2bf(acc[i][j][0] * l0);
            CL[(mb + 1) * 136 + nc] = f2bf(acc[i][j][1] * l1);
            CL[(mb + 2) * 136 + nc] = f2bf(acc[i][j][2] * l2);
            CL[(mb + 3) * 136 + nc] = f2bf(acc[i][j][3] * l3);
        }
    }
    __syncthreads();

    constexpr int WIN = 1 << LG;
    if constexpr (BM == 128) {
        int row = t >> 1, ph = t & 1;
        int tok = m0 + row;
        int oy = tok >> (7 - LG), ox = tok & ((128 >> LG) - 1);
        int pix = (n0 >> 6) + ph;
        int wy = pix >> LG, wx = pix & (WIN - 1);
        int yy = oy * WIN + wy, xx = ox * WIN + wx;
        uint4* dpp = (uint4*)&aot[((size_t)b * HWP + yy * WW_ + xx) * CC + CH0];
        const uint4* spp = (const uint4*)&CL[row * 136 + ph * 64];
#pragma unroll
        for (int e = 0; e < 8; e++) dpp[e] = spp[e];
    } else {
        int row = t >> 2, q4 = t & 3;
        int tok = m0 + row;
        int oy = tok >> (7 - LG), ox = tok & ((128 >> LG) - 1);
        int pix = (n0 >> 6) + (q4 >> 1);
        int wy = pix >> LG, wx = pix & (WIN - 1);
        int yy = oy * WIN + wy, xx = ox * WIN + wx;
        int chb = (q4 & 1) * 32;
        uint4* dpp = (uint4*)&aot[((size_t)b * HWP + yy * WW_ + xx) * CC + CH0 + chb];
        const uint4* spp = (const uint4*)&CL[row * 136 + q4 * 32];
#pragma unroll
        for (int e = 0; e < 4; e++) dpp[e] = spp[e];
    }
}

// ---------------------------------------------------------------------------
// scale-3 S: 64x64, K=16384, MFMA, K-split 16 blocks, fp32 atomic acc.
// grid (16 kc, 4 b). Waves split the 1024-K chunk.
__global__ __launch_bounds__(256) void s3_mfma(
    const unsigned short* __restrict__ Qb, const unsigned short* __restrict__ Kb,
    float* __restrict__ S3, float sc)
{
    int kc = blockIdx.x, b = blockIdx.y;
    const unsigned short* Q = Qb + (size_t)b * TOK;
    const unsigned short* K = Kb + (size_t)b * TOK;
    int t = threadIdx.x, w = t >> 6, lane = t & 63;
    int quad = lane >> 4, lr = lane & 15;
    int k0 = kc * 1024 + w * 256;

    f32x4 acc[4][4];
#pragma unroll
    for (int i = 0; i < 4; i++)
#pragma unroll
        for (int j = 0; j < 4; j++) acc[i][j] = (f32x4){0.f, 0.f, 0.f, 0.f};

    for (int ks = 0; ks < 256; ks += 32) {
        bf16x8 af[4], bfv[4];
#pragma unroll
        for (int i = 0; i < 4; i++)
            af[i] = *(const bf16x8*)&Q[(size_t)(i * 16 + lr) * 16384 + k0 + ks + quad * 8];
#pragma unroll
        for (int j = 0; j < 4; j++)
            bfv[j] = *(const bf16x8*)&K[(size_t)(j * 16 + lr) * 16384 + k0 + ks + quad * 8];
#pragma unroll
        for (int i = 0; i < 4; i++)
#pragma unroll
            for (int j = 0; j < 4; j++)
                acc[i][j] = __builtin_amdgcn_mfma_f32_16x16x32_bf16(af[i], bfv[j], acc[i][j], 0, 0, 0);
    }

    __shared__ float Cl[64 * 68];
    for (int e = t; e < 64 * 68; e += 256) Cl[e] = 0.f;
    __syncthreads();
    for (int ww = 0; ww < 4; ww++) {
        if (w == ww) {
#pragma unroll
            for (int i = 0; i < 4; i++)
#pragma unroll
                for (int j = 0; j < 4; j++)
#pragma unroll
                    for (int rr = 0; rr < 4; rr++)
                        Cl[(i * 16 + quad * 4 + rr) * 68 + j * 16 + lr] += acc[i][j][rr];
        }
        __syncthreads();
    }
    float* Sb = S3 + (size_t)b * 4096;
    for (int e = t; e < 4096; e += 256)
        atomicAdd(&Sb[e], Cl[(e >> 6) * 68 + (e & 63)] * sc);
}

// in-place softmax on fp32 S3 rows (n=64). grid (64, 4)
__global__ __launch_bounds__(256) void softmax3(float* __restrict__ S)
{
    int b = blockIdx.y, row = blockIdx.x;
    float* rp = S + (size_t)b * 4096 + (size_t)row * 64;
    __shared__ float red[256];
    int t = threadIdx.x;
    float m = -1e30f;
    if (t < 64) m = rp[t];
    red[t] = m; __syncthreads();
    for (int s = 128; s > 0; s >>= 1) { if (t < s) red[t] = fmaxf(red[t], red[t + s]); __syncthreads(); }
    m = red[0]; __syncthreads();
    float e = 0.f;
    if (t < 64) { e = __expf(rp[t] - m); }
    red[t] = e; __syncthreads();
    for (int s = 128; s > 0; s >>= 1) { if (t < s) red[t] += red[t + s]; __syncthreads(); }
    float inv = 1.f / red[0];
    if (t < 64) rp[t] = e * inv;
}

// scale-3 O = P V, MFMA. grid (64 d-tiles of 256, 4 b). V3 = [d][tok].
__global__ __launch_bounds__(256) void o3_mfma(
    const float* __restrict__ P, const unsigned short* __restrict__ V3,
    unsigned short* __restrict__ aot)
{
    int b = blockIdx.y, nt = blockIdx.x;
    const float* Pb = P + (size_t)b * 4096;
    const unsigned short* V = V3 + (size_t)b * TOK;
    __shared__ unsigned short Pl[64 * 72];
    int t = threadIdx.x;
    {
        int row = t >> 2, c0 = (t & 3) * 16;
        union { unsigned short us_[16]; uint4 q_[2]; } tmp;
#pragma unroll
        for (int e = 0; e < 16; e += 4) {
            float4 v = *(const float4*)&Pb[row * 64 + c0 + e];
            tmp.us_[e + 0] = f2bf(v.x); tmp.us_[e + 1] = f2bf(v.y);
            tmp.us_[e + 2] = f2bf(v.z); tmp.us_[e + 3] = f2bf(v.w);
        }
        uint4* dp = (uint4*)&Pl[row * 72 + c0];
        dp[0] = tmp.q_[0]; dp[1] = tmp.q_[1];
    }
    __syncthreads();
    int w = t >> 6, lane = t & 63, quad = lane >> 4, lr = lane & 15;
    int d0 = nt * 256 + w * 64;

    f32x4 acc[4][4];
#pragma unroll
    for (int i = 0; i < 4; i++)
#pragma unroll
        for (int j = 0; j < 4; j++) acc[i][j] = (f32x4){0.f, 0.f, 0.f, 0.f};

#pragma unroll
    for (int s = 0; s < 2; s++) {
        bf16x8 af[4], bfv[4];
#pragma unroll
        for (int i = 0; i < 4; i++)
            af[i] = *(const bf16x8*)&Pl[(i * 16 + lr) * 72 + s * 32 + quad * 8];
#pragma unroll
        for (int j = 0; j < 4; j++)
            bfv[j] = *(const bf16x8*)&V[(size_t)(d0 + j * 16 + lr) * 64 + s * 32 + quad * 8];
#pragma unroll
        for (int i = 0; i < 4; i++)
#pragma unroll
            for (int j = 0; j < 4; j++)
                acc[i][j] = __builtin_amdgcn_mfma_f32_16x16x32_bf16(af[i], bfv[j], acc[i][j], 0, 0, 0);
    }

    int pix = d0 >> 6;                  // one pixel position per wave
    int wy = pix >> 4, wx = pix & 15;
#pragma unroll
    for (int i = 0; i < 4; i++) {
#pragma unroll
        for (int rr = 0; rr < 4; rr++) {
            int tok = i * 16 + quad * 4 + rr;
            int oy = tok >> 3, ox = tok & 7;
            int yy = oy * 16 + wy, xx = ox * 16 + wx;
            size_t base = ((size_t)b * HWP + yy * WW_ + xx) * CC + 192;
#pragma unroll
            for (int j = 0; j < 4; j++)
                aot[base + j * 16 + lr] = f2bf(acc[i][j][rr]);
        }
    }
}

// ---------------------------------------------------------------------------
// conv3x3 via tap-major GEMM on NHWC bf16. grid: (128 y-rows, 2 o-tiles, 4 b)
__global__ __launch_bounds__(256) void conv_gemm(
    const unsigned short* __restrict__ aot, const unsigned short* __restrict__ wpack,
    const float* __restrict__ bo, float* __restrict__ zout)
{
    __shared__ unsigned short SMEM[128 * 72 * 2];
    unsigned short* As = SMEM;
    unsigned short* Bs = SMEM + 128 * 72;

    int yrow = blockIdx.x;
    int o0 = blockIdx.y * 128;
    int b = blockIdx.z;
    const unsigned short* aob = aot + (size_t)b * HWP * CC;
    const unsigned short* wsrc = wpack + (size_t)o0 * 2304;

    int t = threadIdx.x, w = t >> 6, lane = t & 63;
    int quad = lane >> 4, lr = lane & 15;
    int woffm = (w >> 1) * 64, woffn = (w & 1) * 64;

    f32x4 acc[4][4];
#pragma unroll
    for (int i = 0; i < 4; i++)
#pragma unroll
        for (int j = 0; j < 4; j++) acc[i][j] = (f32x4){0.f, 0.f, 0.f, 0.f};

    for (int tap = 0; tap < 9; tap++) {
        int dy = tap / 3 - 1, dx = tap % 3 - 1;
        int ys = yrow + dy;
        for (int cb = 0; cb < CC; cb += 64) {
            TileU TA, TB;
            tile_load<128>(TA, wsrc + tap * CC + cb, 2304, t);
            {
                int r = t >> 1, kc = (t & 1) * 32;
                int xs = r + dx;
                if (ys >= 0 && ys < HH_ && xs >= 0 && xs < WW_) {
                    const uint4* sp = (const uint4*)(aob + ((size_t)ys * WW_ + xs) * CC + cb + kc);
                    TB.q[0] = sp[0]; TB.q[1] = sp[1]; TB.q[2] = sp[2]; TB.q[3] = sp[3];
                } else {
                    uint4 zz = make_uint4(0, 0, 0, 0);
                    TB.q[0] = zz; TB.q[1] = zz; TB.q[2] = zz; TB.q[3] = zz;
                }
            }
            __syncthreads();
            tile_store<128>(As, TA, t);
            tile_store<128>(Bs, TB, t);
            __syncthreads();
            mfma_iterT<4, 4>(As, Bs, woffm, woffn, lr, quad, acc);
            __syncthreads();
        }
    }

#pragma unroll
    for (int i = 0; i < 4; i++) {
        int ob = o0 + woffm + i * 16 + quad * 4;
#pragma unroll
        for (int j = 0; j < 4; j++) {
            int xp = woffn + j * 16 + lr;
#pragma unroll
            for (int rr = 0; rr < 4; rr++) {
                int o = ob + rr;
                zout[((size_t)(b * CC + o)) * HWP + yrow * WW_ + xp] =
                    acc[i][j][rr] + bo[o];
            }
        }
    }
}

// ---------------------------------------------------------------------------
__global__ __launch_bounds__(256) void bn_stats_kernel(
    const float* __restrict__ z, const float* __restrict__ gamma,
    const float* __restrict__ beta, float* __restrict__ stats)
{
    int c = blockIdx.x;
    int t = threadIdx.x;
    float s = 0.f, s2 = 0.f;
    for (int i = t; i < 4 * HWP; i += 256) {
        int b = i >> 14, p = i & (HWP - 1);
        float v = z[(((size_t)b * CC + c) << 14) + p];
        s += v; s2 = fmaf(v, v, s2);
    }
    __shared__ float r1[256], r2[256];
    r1[t] = s; r2[t] = s2; __syncthreads();
    for (int st = 128; st > 0; st >>= 1) {
        if (t < st) { r1[t] += r1[t + st]; r2[t] += r2[t + st]; }
        __syncthreads();
    }
    if (t == 0) {
        float inv_n = 1.f / (4 * HWP);
        float mean = r1[0] * inv_n;
        float var = r2[0] * inv_n - mean * mean;
        float rstd = rsqrtf(var + 1e-5f);
        float gs = gamma[c] * rstd;
        stats[c] = gs;
        stats[CC + c] = beta[c] - mean * gs;
    }
}

__global__ __launch_bounds__(256) void bn_apply_kernel(
    float* __restrict__ z, const float* __restrict__ stats)
{
    size_t i4 = (size_t)blockIdx.x * 256 + threadIdx.x;
    size_t idx = i4 * 4;
    int c = (int)((idx >> 14) & 255);
    float gs = stats[c], gb = stats[CC + c];
    float4 v = *(float4*)&z[idx];
    v.x = fmaf(v.x, gs, gb); v.y = fmaf(v.y, gs, gb);
    v.z = fmaf(v.z, gs, gb); v.w = fmaf(v.w, gs, gb);
    v.x = v.x >= 0.f ? v.x : 0.2f * v.x;
    v.y = v.y >= 0.f ? v.y : 0.2f * v.y;
    v.z = v.z >= 0.f ? v.z : 0.2f * v.z;
    v.w = v.w >= 0.f ? v.w : 0.2f * v.w;
    *(float4*)&z[idx] = v;
}

// ---------------------------------------------------------------------------
extern "C" void kernel_launch(void* const* d_in, const int* in_sizes, int n_in,
                              void* d_out, int out_size, void* d_ws, size_t ws_size,
                              hipStream_t stream)
{
    const float* x     = (const float*)d_in[0];
    const float* y     = (const float*)d_in[1];
    const float* Wq    = (const float*)d_in[2];
    const float* bq    = (const float*)d_in[3];
    const float* Wk    = (const float*)d_in[4];
    const float* bk    = (const float*)d_in[5];
    const float* Wv    = (const float*)d_in[6];
    const float* bv    = (const float*)d_in[7];
    const float* Wo    = (const float*)d_in[8];
    const float* bo    = (const float*)d_in[9];
    const float* gamma = (const float*)d_in[10];
    const float* beta  = (const float*)d_in[11];
    float* out = (float*)d_out;

    unsigned short* qt    = (unsigned short*)d_ws;
    unsigned short* kt    = qt + (size_t)16777216;
    unsigned short* vt    = kt + (size_t)16777216;
    unsigned short* aot   = vt + (size_t)16777216;
    unsigned short* Sbf   = aot + (size_t)16777216;
    unsigned short* wpack = Sbf + (size_t)16777216;
    unsigned short* wqkv  = wpack + (size_t)589824;
    float* stats = (float*)(wqkv + (size_t)196608);
    float* mstat = stats + 512;
    float* linv  = mstat + 4096;
    float* S3    = linv + 4096;

    dim3 blk(256);

    pack_wqkv<<<dim3(768), blk, 0, stream>>>(Wq, Wk, Wv, wqkv);
    wpack_kernel<<<dim3(256), blk, 0, stream>>>(Wo, wpack);
    zero_kernel<<<dim3(64), blk, 0, stream>>>(S3);

    proj_gemm<<<dim3(128, 2, 12), blk, 0, stream>>>(
        x, y, wqkv, bq, bk, bv, qt, kt, vt);

    // scale 0: n=4096, D=256, win 2 — per batch (Sbf reused)
    for (int b = 0; b < 4; b++) {
        s_gemm<4096, 256, 128, 128, 4, 4><<<dim3(32, 32, 1), blk, 0, stream>>>(
            kt + (size_t)b * TOK, qt + (size_t)b * TOK, Sbf, 1.f / 16.f);
        row_stats<<<dim3(1024), blk, 0, stream>>>(Sbf, mstat, linv, 4096);
        o_gemm<4096, 256, 1, 0, 64, 2, 4><<<dim3(2, 64, 1), blk, 0, stream>>>(
            Sbf, vt + (size_t)b * TOK, mstat, linv, aot, b);
    }
    // scale 1: n=1024, D=1024, win 4 (batched)
    s_gemm<1024, 1024, 128, 128, 4, 4><<<dim3(8, 8, 4), blk, 0, stream>>>(
        kt + (size_t)4 * TOK, qt + (size_t)4 * TOK, Sbf, 1.f / 32.f);
    row_stats<<<dim3(1024), blk, 0, stream>>>(Sbf, mstat, linv, 1024);
    o_gemm<1024, 1024, 2, 64, 128, 4, 4><<<dim3(8, 8, 4), blk, 0, stream>>>(
        Sbf, vt + (size_t)4 * TOK, mstat, linv, aot, 0);
    // scale 2: n=256, D=4096, win 8
    s_gemm<256, 4096, 64, 64, 2, 2><<<dim3(4, 4, 4), blk, 0, stream>>>(
        kt + (size_t)8 * TOK, qt + (size_t)8 * TOK, Sbf, 1.f / 64.f);
    row_stats<<<dim3(256), blk, 0, stream>>>(Sbf, mstat, linv, 256);
    o_gemm<256, 4096, 3, 128, 128, 4, 4><<<dim3(32, 2, 4), blk, 0, stream>>>(
        Sbf, vt + (size_t)8 * TOK, mstat, linv, aot, 0);
    // scale 3: n=64, D=16384, win 16 — MFMA K-split + tiny softmax
    s3_mfma<<<dim3(16, 4), blk, 0, stream>>>(
        qt + (size_t)12 * TOK, kt + (size_t)12 * TOK, S3, 1.f / 128.f);
    softmax3<<<dim3(64, 4), blk, 0, stream>>>(S3);
    o3_mfma<<<dim3(64, 4), blk, 0, stream>>>(S3, vt + (size_t)12 * TOK, aot);

    conv_gemm<<<dim3(128, 2, 4), blk, 0, stream>>>(aot, wpack, bo, out);
    bn_stats_kernel<<<dim3(CC), blk, 0, stream>>>(out, gamma, beta, stats);
    bn_apply_kernel<<<dim3(16384), blk, 0, stream>>>(out, stats);
}